// Round 1
// baseline (1123.886 us; speedup 1.0000x reference)
//
#include <hip/hip_runtime.h>
#include <stdint.h>

#define B 8
#define N 8192
#define NG 512
#define GS 32

typedef unsigned long long ull;

// Exact (no-FMA, left-to-right) squared distance: ((dx*dx + dy*dy) + dz*dz)
__device__ __forceinline__ float sq3(float dx, float dy, float dz) {
#pragma clang fp contract(off)
  return dx * dx + dy * dy + dz * dz;
}

// ---------------- Kernel 1: SE(3) transform, AoS xyz -> SoA xs/ys/zs ------
__global__ void transform_k(const float* __restrict__ xyz,
                            const float* __restrict__ pose,
                            float* __restrict__ xs, float* __restrict__ ys,
                            float* __restrict__ zs) {
#pragma clang fp contract(off)
  int i = blockIdx.x * blockDim.x + threadIdx.x;
  if (i >= B * N) return;
  int b = i / N;
  const float* P = pose + b * 12;  // (3,4) row-major: R|t
  float p0 = xyz[i * 3 + 0], p1 = xyz[i * 3 + 1], p2 = xyz[i * 3 + 2];
  // exact order: ((r0*p0 + r1*p1) + r2*p2) + t
  float ox = ((P[0] * p0 + P[1] * p1) + P[2] * p2) + P[3];
  float oy = ((P[4] * p0 + P[5] * p1) + P[6] * p2) + P[7];
  float oz = ((P[8] * p0 + P[9] * p1) + P[10] * p2) + P[11];
  xs[i] = ox;
  ys[i] = oy;
  zs[i] = oz;
}

// ---------------- Kernel 2: farthest point sampling, 1 block per batch ----
#define FPS_T 1024
#define FPS_P (N / FPS_T)  // 8 points per thread

__global__ __launch_bounds__(FPS_T) void fps_k(const float* __restrict__ xs,
                                               const float* __restrict__ ys,
                                               const float* __restrict__ zs,
                                               float* __restrict__ centers) {
#pragma clang fp contract(off)
  int b = blockIdx.x;
  int t = threadIdx.x;
  __shared__ float cur[3];             // current "last" point coords
  __shared__ ull wred[FPS_T / 64];     // per-wave reduction partials
  __shared__ float cbuf[NG * 3];       // buffered centers (flush at end)

  const float* bx = xs + b * N;
  const float* by = ys + b * N;
  const float* bz = zs + b * N;

  float px[FPS_P], py[FPS_P], pz[FPS_P], dist[FPS_P];
#pragma unroll
  for (int j = 0; j < FPS_P; ++j) {
    int p = j * FPS_T + t;
    px[j] = bx[p];
    py[j] = by[p];
    pz[j] = bz[p];
    dist[j] = 1e10f;  // matches jnp.full(..., 1e10, f32)
  }
  if (t == 0) { cur[0] = px[0]; cur[1] = py[0]; cur[2] = pz[0]; }  // last=0
  __syncthreads();

  for (int k = 0; k < NG; ++k) {
    float lx = cur[0], ly = cur[1], lz = cur[2];
    if (t < 3) cbuf[k * 3 + t] = cur[t];  // emit 'last' BEFORE update (scan order)

    // exact min-update + local max of dist
    float vmax = -1.0f;
#pragma unroll
    for (int j = 0; j < FPS_P; ++j) {
      float dx = px[j] - lx, dy = py[j] - ly, dz = pz[j] - lz;
      float d = sq3(dx, dy, dz);
      dist[j] = fminf(dist[j], d);
      vmax = fmaxf(vmax, dist[j]);
    }
    // smallest local index achieving vmax (argmax-first semantics)
    int cand = 0x7fffffff;
#pragma unroll
    for (int j = 0; j < FPS_P; ++j) {
      int p = j * FPS_T + t;
      cand = min(cand, (dist[j] == vmax) ? p : 0x7fffffff);
    }
    // pack: max over key == max dist, tie -> min index
    ull key = ((ull)__float_as_uint(vmax) << 32) | (ull)(unsigned)(N - 1 - cand);
#pragma unroll
    for (int off = 32; off >= 1; off >>= 1) {
      ull o = __shfl_xor(key, off, 64);
      key = (o > key) ? o : key;
    }
    if ((t & 63) == 0) wred[t >> 6] = key;
    __syncthreads();

    ull gk = wred[0];
#pragma unroll
    for (int w = 1; w < FPS_T / 64; ++w) {
      ull o = wred[w];
      gk = (o > gk) ? o : gk;
    }
    int nidx = N - 1 - (int)(unsigned)gk;

    // owner lane publishes winner coords (register -> LDS, no global traffic)
    if (t == (nidx & (FPS_T - 1))) {
      int jj = nidx / FPS_T;
#pragma unroll
      for (int j = 0; j < FPS_P; ++j)
        if (j == jj) { cur[0] = px[j]; cur[1] = py[j]; cur[2] = pz[j]; }
    }
    __syncthreads();  // publishes cur; also protects wred for next iteration
  }

  // flush centers (B, NG, 3)
  for (int i = t; i < NG * 3; i += FPS_T) centers[b * NG * 3 + i] = cbuf[i];
}

// ---------------- Kernel 3: exact 32-NN per center, 1 block per center ----
#define KNN_T 256
#define KNN_P (N / KNN_T)  // 32 points per thread

__global__ __launch_bounds__(KNN_T) void knn_k(const float* __restrict__ xs,
                                               const float* __restrict__ ys,
                                               const float* __restrict__ zs,
                                               const float* __restrict__ centers,
                                               float* __restrict__ out) {
#pragma clang fp contract(off)
  int b = blockIdx.y, g = blockIdx.x, t = threadIdx.x;
  const float* bx = xs + b * N;
  const float* by = ys + b * N;
  const float* bz = zs + b * N;
  int ci = (b * NG + g) * 3;
  float cx = centers[ci], cy = centers[ci + 1], cz = centers[ci + 2];

  // packed keys: (distBits<<32)|idx ; min over key == min dist, tie -> min idx
  ull key[KNN_P];
  ull lmin = ~0ull;
#pragma unroll
  for (int j = 0; j < KNN_P; ++j) {
    int p = j * KNN_T + t;
    float dx = bx[p] - cx, dy = by[p] - cy, dz = bz[p] - cz;
    float d = sq3(dx, dy, dz);
    key[j] = ((ull)__float_as_uint(d) << 32) | (ull)(unsigned)p;
    lmin = (key[j] < lmin) ? key[j] : lmin;
  }

  __shared__ ull wred[KNN_T / 64];
  __shared__ int widx[GS];

  for (int k = 0; k < GS; ++k) {
    ull v = lmin;
#pragma unroll
    for (int off = 32; off >= 1; off >>= 1) {
      ull o = __shfl_xor(v, off, 64);
      v = (o < v) ? o : v;
    }
    if ((t & 63) == 0) wred[t >> 6] = v;
    __syncthreads();

    ull gm = wred[0];
#pragma unroll
    for (int w = 1; w < KNN_T / 64; ++w) {
      ull o = wred[w];
      gm = (o < gm) ? o : gm;
    }
    int idx = (int)(unsigned)gm;

    // only the owning lane rescans its keys (cached local min elsewhere)
    if (t == (idx & (KNN_T - 1))) {
      int jj = idx / KNN_T;
#pragma unroll
      for (int j = 0; j < KNN_P; ++j)
        if (j == jj) key[j] = ~0ull;
      lmin = ~0ull;
#pragma unroll
      for (int j = 0; j < KNN_P; ++j) lmin = (key[j] < lmin) ? key[j] : lmin;
    }
    if (t == 0) widx[k] = idx;
    __syncthreads();
  }

  // gather & write neighborhood (B, NG, GS, 3), k ascending by (d, idx)
  if (t < GS) {
    int idx = widx[t];
    int o = ((b * NG + g) * GS + t) * 3;
    out[o + 0] = bx[idx];
    out[o + 1] = by[idx];
    out[o + 2] = bz[idx];
  }
}

extern "C" void kernel_launch(void* const* d_in, const int* in_sizes, int n_in,
                              void* d_out, int out_size, void* d_ws, size_t ws_size,
                              hipStream_t stream) {
  const float* xyz = (const float*)d_in[0];   // (B, N, 3) f32
  const float* pose = (const float*)d_in[1];  // (B, 3, 4) f32
  float* out = (float*)d_out;                 // neighborhood (B,NG,GS,3) ++ center (B,NG,3)

  float* xs = (float*)d_ws;       // SoA transformed points
  float* ys = xs + B * N;
  float* zs = ys + B * N;
  float* centers = out + B * NG * GS * 3;  // center block of d_out

  transform_k<<<dim3((B * N + 255) / 256), dim3(256), 0, stream>>>(xyz, pose, xs, ys, zs);
  fps_k<<<dim3(B), dim3(FPS_T), 0, stream>>>(xs, ys, zs, centers);
  knn_k<<<dim3(NG, B), dim3(KNN_T), 0, stream>>>(xs, ys, zs, centers, out);
}

// Round 2
// 875.949 us; speedup vs baseline: 1.2831x; 1.2831x over previous
//
#include <hip/hip_runtime.h>
#include <stdint.h>

#define B 8
#define N 8192
#define NG 512
#define GS 32

typedef unsigned long long ull;
typedef float v2f __attribute__((ext_vector_type(2)));

// Exact (no-FMA, left-to-right) squared distance: ((dx*dx + dy*dy) + dz*dz)
__device__ __forceinline__ float sq3(float dx, float dy, float dz) {
#pragma clang fp contract(off)
  return dx * dx + dy * dy + dz * dz;
}

// ---------------- Kernel 1: SE(3) transform, AoS xyz -> SoA xs/ys/zs ------
__global__ void transform_k(const float* __restrict__ xyz,
                            const float* __restrict__ pose,
                            float* __restrict__ xs, float* __restrict__ ys,
                            float* __restrict__ zs) {
#pragma clang fp contract(off)
  int i = blockIdx.x * blockDim.x + threadIdx.x;
  if (i >= B * N) return;
  int b = i / N;
  const float* P = pose + b * 12;  // (3,4) row-major: R|t
  float p0 = xyz[i * 3 + 0], p1 = xyz[i * 3 + 1], p2 = xyz[i * 3 + 2];
  // exact order: ((r0*p0 + r1*p1) + r2*p2) + t
  float ox = ((P[0] * p0 + P[1] * p1) + P[2] * p2) + P[3];
  float oy = ((P[4] * p0 + P[5] * p1) + P[6] * p2) + P[7];
  float oz = ((P[8] * p0 + P[9] * p1) + P[10] * p2) + P[11];
  xs[i] = ox;
  ys[i] = oy;
  zs[i] = oz;
}

// ---------------- Kernel 2: farthest point sampling, 1 block per batch ----
// 512 threads, 8 float2 (=16 points) per thread, ONE barrier per step.
#define FPS_T 512
#define FPS_J (N / FPS_T / 2)  // 8 float2 per thread

__global__ __launch_bounds__(FPS_T) void fps_k(const float* __restrict__ xs,
                                               const float* __restrict__ ys,
                                               const float* __restrict__ zs,
                                               float* __restrict__ centers) {
#pragma clang fp contract(off)
  int b = blockIdx.x;
  int t = threadIdx.x;
  __shared__ ull wred[2][FPS_T / 64];  // double-buffered per-wave partials
  __shared__ float cbuf[NG * 3];       // buffered centers (flush at end)

  const float* __restrict__ bx = xs + b * N;
  const float* __restrict__ by = ys + b * N;
  const float* __restrict__ bz = zs + b * N;
  const v2f* __restrict__ bx2 = (const v2f*)bx;
  const v2f* __restrict__ by2 = (const v2f*)by;
  const v2f* __restrict__ bz2 = (const v2f*)bz;

  // point (j, t, e) has global index p = (j*FPS_T + t)*2 + e
  v2f px[FPS_J], py[FPS_J], pz[FPS_J], dist[FPS_J];
#pragma unroll
  for (int j = 0; j < FPS_J; ++j) {
    int q = j * FPS_T + t;
    px[j] = bx2[q];
    py[j] = by2[q];
    pz[j] = bz2[q];
    dist[j].x = 1e10f;  // matches jnp.full(..., 1e10, f32)
    dist[j].y = 1e10f;
  }

  int nidx = 0;  // jnp: last = 0 at step 0
  for (int k = 0; k < NG; ++k) {
    // broadcast load of current "last" point (same addr all lanes -> L2 hit)
    float lx = bx[nidx], ly = by[nidx], lz = bz[nidx];
    if (t == 0) {  // emit 'last' BEFORE update (scan output order)
      cbuf[k * 3 + 0] = lx;
      cbuf[k * 3 + 1] = ly;
      cbuf[k * 3 + 2] = lz;
    }

    // exact min-update + local max (packed f32: pk_mul/pk_add, same rounding)
    float vmax = -1.0f;
#pragma unroll
    for (int j = 0; j < FPS_J; ++j) {
      v2f dx = px[j] - lx, dy = py[j] - ly, dz = pz[j] - lz;
      v2f d = (dx * dx + dy * dy) + dz * dz;
      v2f dm;
      dm.x = fminf(dist[j].x, d.x);
      dm.y = fminf(dist[j].y, d.y);
      dist[j] = dm;
      vmax = fmaxf(vmax, fmaxf(dm.x, dm.y));
    }
    // smallest local index achieving vmax (argmax-first semantics)
    int cand = 0x7fffffff;
#pragma unroll
    for (int j = 0; j < FPS_J; ++j) {
      int p = (j * FPS_T + t) * 2;
      cand = min(cand, (dist[j].x == vmax) ? p : 0x7fffffff);
      cand = min(cand, (dist[j].y == vmax) ? (p + 1) : 0x7fffffff);
    }
    // pack: max over key == max dist, tie -> min index
    ull key = ((ull)__float_as_uint(vmax) << 32) | (ull)(unsigned)(N - 1 - cand);
#pragma unroll
    for (int off = 32; off >= 1; off >>= 1) {
      ull o = __shfl_xor(key, off, 64);
      key = (o > key) ? o : key;
    }
    if ((t & 63) == 0) wred[k & 1][t >> 6] = key;
    __syncthreads();

    ull gk = wred[k & 1][0];
#pragma unroll
    for (int w = 1; w < FPS_T / 64; ++w) {
      ull o = wred[k & 1][w];
      gk = (o > gk) ? o : gk;
    }
    nidx = N - 1 - (int)(unsigned)gk;
    // no second barrier: next iter writes wred[(k+1)&1] (other buffer)
  }

  // flush centers (B, NG, 3)
  for (int i = t; i < NG * 3; i += FPS_T) centers[b * NG * 3 + i] = cbuf[i];
}

// ---------------- Kernel 3: exact 32-NN per center, 1 block per center ----
#define KNN_T 256
#define KNN_P (N / KNN_T)  // 32 points per thread

__global__ __launch_bounds__(KNN_T) void knn_k(const float* __restrict__ xs,
                                               const float* __restrict__ ys,
                                               const float* __restrict__ zs,
                                               const float* __restrict__ centers,
                                               float* __restrict__ out) {
#pragma clang fp contract(off)
  int b = blockIdx.y, g = blockIdx.x, t = threadIdx.x;
  const float* bx = xs + b * N;
  const float* by = ys + b * N;
  const float* bz = zs + b * N;
  int ci = (b * NG + g) * 3;
  float cx = centers[ci], cy = centers[ci + 1], cz = centers[ci + 2];

  // packed keys: (distBits<<32)|idx ; min over key == min dist, tie -> min idx
  ull key[KNN_P];
  ull lmin = ~0ull;
#pragma unroll
  for (int j = 0; j < KNN_P; ++j) {
    int p = j * KNN_T + t;
    float dx = bx[p] - cx, dy = by[p] - cy, dz = bz[p] - cz;
    float d = sq3(dx, dy, dz);
    key[j] = ((ull)__float_as_uint(d) << 32) | (ull)(unsigned)p;
    lmin = (key[j] < lmin) ? key[j] : lmin;
  }

  __shared__ ull wred[KNN_T / 64];
  __shared__ int widx[GS];

  for (int k = 0; k < GS; ++k) {
    ull v = lmin;
#pragma unroll
    for (int off = 32; off >= 1; off >>= 1) {
      ull o = __shfl_xor(v, off, 64);
      v = (o < v) ? o : v;
    }
    if ((t & 63) == 0) wred[t >> 6] = v;
    __syncthreads();

    ull gm = wred[0];
#pragma unroll
    for (int w = 1; w < KNN_T / 64; ++w) {
      ull o = wred[w];
      gm = (o < gm) ? o : gm;
    }
    int idx = (int)(unsigned)gm;

    // only the owning lane rescans its keys (cached local min elsewhere)
    if (t == (idx & (KNN_T - 1))) {
      int jj = idx / KNN_T;
#pragma unroll
      for (int j = 0; j < KNN_P; ++j)
        if (j == jj) key[j] = ~0ull;
      lmin = ~0ull;
#pragma unroll
      for (int j = 0; j < KNN_P; ++j) lmin = (key[j] < lmin) ? key[j] : lmin;
    }
    if (t == 0) widx[k] = idx;
    __syncthreads();
  }

  // gather & write neighborhood (B, NG, GS, 3), k ascending by (d, idx)
  if (t < GS) {
    int idx = widx[t];
    int o = ((b * NG + g) * GS + t) * 3;
    out[o + 0] = bx[idx];
    out[o + 1] = by[idx];
    out[o + 2] = bz[idx];
  }
}

extern "C" void kernel_launch(void* const* d_in, const int* in_sizes, int n_in,
                              void* d_out, int out_size, void* d_ws, size_t ws_size,
                              hipStream_t stream) {
  const float* xyz = (const float*)d_in[0];   // (B, N, 3) f32
  const float* pose = (const float*)d_in[1];  // (B, 3, 4) f32
  float* out = (float*)d_out;                 // neighborhood (B,NG,GS,3) ++ center (B,NG,3)

  float* xs = (float*)d_ws;       // SoA transformed points
  float* ys = xs + B * N;
  float* zs = ys + B * N;
  float* centers = out + B * NG * GS * 3;  // center block of d_out

  transform_k<<<dim3((B * N + 255) / 256), dim3(256), 0, stream>>>(xyz, pose, xs, ys, zs);
  fps_k<<<dim3(B), dim3(FPS_T), 0, stream>>>(xs, ys, zs, centers);
  knn_k<<<dim3(NG, B), dim3(KNN_T), 0, stream>>>(xs, ys, zs, centers, out);
}